// Round 10
// baseline (251.970 us; speedup 1.0000x reference)
//
#include <hip/hip_runtime.h>

// LongformerAttention on MI355X (gfx950), fp16 MFMA pipeline, round 17.
// R17: 8-phase-template port for both dense GEMMs (guide m201: 62% MfmaUtil
// at 1 block/CU proves fine interleave beats TLP). Tile 256x128, BK=64,
// 512 thr (8 waves 4m x 2n), acc[4][4]/wave. LDS 3 buffers x 48KB = 144KB:
// the 3-buffer ring makes a 2-K-tile prefetch distance RACE-FREE (stage T+2
// into T-1's buffer, whose reads retired >=2 barriers earlier). 6 loads/
// thread/K-tile issued 3+3 inside the two compute phases; counted
// s_waitcnt vmcnt(6) ONCE per K-tile before the trailing barrier (T+1 lands
// under T's compute; queue never drains mid-loop); vmcnt->barrier->ds_read
// order for cross-wave visibility. Per phase: {8 ds_read_b128 + 3 stage ->
// barrier -> lgkmcnt(0)+sched_barrier -> setprio(1) 16 MFMA setprio(0) ->
// barrier}. R7-proven LDS row geometry/chunk swizzle/MFMA convention/
// epilogues re-indexed for the 256-row tile. qkv grid 768x512t (XCD: 2MB
// A-panel + 2MB B = L2-fit), out 256x512t. Attn/convert = R10 verbatim.
// Failed-arc ledger: R8/R11/R12/R13/R16 structural edits all lost to R10
// (226.0us); this is the remaining documented path (+28-41% T3/T4, +21-39%
// T5 on 8-phase). If it regresses, R10 is the ship.

typedef _Float16 half8 __attribute__((ext_vector_type(8)));
typedef _Float16 half4v __attribute__((ext_vector_type(4)));
typedef float floatx4 __attribute__((ext_vector_type(4)));

typedef __attribute__((address_space(3))) unsigned int lds_u32;
typedef const __attribute__((address_space(1))) unsigned int glb_u32;

__device__ __forceinline__ void async_copy16(const void* g, void* l) {
  // global -> LDS direct, 16 B/lane. LDS dest = wave-uniform base + lane*16.
  __builtin_amdgcn_global_load_lds((glb_u32*)g, (lds_u32*)l, 16, 0, 0);
}

// ---------------------------------------------------------------- convert
__global__ __launch_bounds__(256) void convert_kernel(
    const float* __restrict__ x, const float* __restrict__ wq,
    const float* __restrict__ wk, const float* __restrict__ wv,
    const float* __restrict__ wo, _Float16* __restrict__ dst) {
  const int e0 = (blockIdx.x * 256 + threadIdx.x) * 4;
  const float* src; int off;
  if      (e0 <  8388608) { src = x;  off = e0; }
  else if (e0 <  9437184) { src = wq; off = e0 -  8388608; }
  else if (e0 < 10485760) { src = wk; off = e0 -  9437184; }
  else if (e0 < 11534336) { src = wv; off = e0 - 10485760; }
  else                    { src = wo; off = e0 - 11534336; }
  const float4 f = *(const float4*)(src + off);
  half4v h;
  h[0] = (_Float16)f.x; h[1] = (_Float16)f.y;
  h[2] = (_Float16)f.z; h[3] = (_Float16)f.w;
  *(half4v*)(dst + e0) = h;
}

// -------------------------------------------- 256x128 8-phase GEMM mainloop
// C[256x128] tile, K=1024 in 16 BK=64 tiles. 8 waves: wm=w>>1 (m quarter,
// 64 rows), wn=w&1 (n half, 64 cols). Per wave acc[4][4] (16x16 frags).
// LDS buf (24576 halfs): A[256][64] chunk-swizzled + B[128][64]. 3 bufs.
__device__ __forceinline__ void mainloop_8ph(
    const _Float16* __restrict__ A, const _Float16* __restrict__ B,
    _Float16* smem, const int m0, const int n0, floatx4 (&acc)[4][4]) {
  const int tid = threadIdx.x;
  const int w = tid >> 6, lane = tid & 63;
  const int l4 = lane & 15, quad = lane >> 4;
  const int wm = w >> 1, wn = w & 1;

  // stage sources: position p = i*512+tid, row r = p>>3, chunk c=(p&7)^(r&7)
  int asrc[4], bsrc[2];
#pragma unroll
  for (int i = 0; i < 4; ++i) {
    const int p = i * 512 + tid;
    const int r = p >> 3, c = (p & 7) ^ (r & 7);
    asrc[i] = (m0 + r) * 1024 + c * 8;
  }
#pragma unroll
  for (int i = 0; i < 2; ++i) {
    const int p = i * 512 + tid;
    const int r = p >> 3, c = (p & 7) ^ (r & 7);
    bsrc[i] = (n0 + r) * 1024 + c * 8;
  }
  const int dl = w * 512;                  // wave-uniform LDS dest (halfs)

  const int arow = (wm * 64 + l4) * 64;    // + mt*1024
  const int brow = (wn * 64 + l4) * 64;    // + nt*1024

#pragma unroll
  for (int i = 0; i < 4; ++i)
#pragma unroll
    for (int j = 0; j < 4; ++j) acc[i][j] = (floatx4){0.f, 0.f, 0.f, 0.f};

  auto stage_full = [&](int bufbase, int kt) {   // 6 loads (prologue only)
    _Float16* Ad = smem + bufbase;
    _Float16* Bd = Ad + 16384;
    const int k0 = kt * 64;
#pragma unroll
    for (int i = 0; i < 4; ++i) async_copy16(A + asrc[i] + k0, Ad + i * 4096 + dl);
#pragma unroll
    for (int i = 0; i < 2; ++i) async_copy16(B + bsrc[i] + k0, Bd + i * 4096 + dl);
  };

  stage_full(0, 0);
  stage_full(24576, 1);
  asm volatile("s_waitcnt vmcnt(6)" ::: "memory");  // T0 landed; T1 in flight
  __builtin_amdgcn_s_barrier();

  int cb = 0, pb = 49152;   // LDS offsets: buf of T, buf of T+2 (ring of 3)
  for (int T = 0; T < 16; ++T) {
    const _Float16* As = smem + cb;
    const _Float16* Bs = As + 16384;
    const bool pf = (T + 2) < 16;
    _Float16* Ad = smem + pb;
    _Float16* Bd = Ad + 16384;
    const int k2 = (T + 2) * 64;

#pragma unroll
    for (int ks = 0; ks < 2; ++ks) {
      // --- phase: ds-reads + stage-issue, barrier, lgkm, MFMA, barrier ---
      half8 af[4], bf[4];
      const int ch = ((ks * 4 + quad) ^ (l4 & 7)) * 8;
#pragma unroll
      for (int mt = 0; mt < 4; ++mt)
        af[mt] = *(const half8*)(As + arow + mt * 1024 + ch);
#pragma unroll
      for (int nt = 0; nt < 4; ++nt)
        bf[nt] = *(const half8*)(Bs + brow + nt * 1024 + ch);
      if (pf) {   // stage T+2 into T-1's buffer (reads retired 2 barriers ago)
        if (ks == 0) {
          async_copy16(A + asrc[0] + k2, Ad + dl);
          async_copy16(A + asrc[1] + k2, Ad + 4096 + dl);
          async_copy16(B + bsrc[0] + k2, Bd + dl);
        } else {
          async_copy16(A + asrc[2] + k2, Ad + 8192 + dl);
          async_copy16(A + asrc[3] + k2, Ad + 12288 + dl);
          async_copy16(B + bsrc[1] + k2, Bd + 4096 + dl);
        }
      }
      __builtin_amdgcn_s_barrier();
      asm volatile("s_waitcnt lgkmcnt(0)" ::: "memory");
      __builtin_amdgcn_sched_barrier(0);
      __builtin_amdgcn_s_setprio(1);
#pragma unroll
      for (int mt = 0; mt < 4; ++mt)
#pragma unroll
        for (int nt = 0; nt < 4; ++nt)
          acc[mt][nt] = __builtin_amdgcn_mfma_f32_16x16x32_f16(af[mt], bf[nt], acc[mt][nt], 0, 0, 0);
      __builtin_amdgcn_s_setprio(0);
      if (ks == 1) {
        // once per K-tile: T+1 must be landed for next iteration's reads;
        // in flight = T+2's 6 loads (issued this K-tile). Never 0 mid-loop.
        if (T < 14) asm volatile("s_waitcnt vmcnt(6)" ::: "memory");
        else        asm volatile("s_waitcnt vmcnt(0)" ::: "memory");
      }
      __builtin_amdgcn_s_barrier();
    }
    cb += 24576; if (cb == 73728) cb = 0;
    pb += 24576; if (pb == 73728) pb = 0;
  }
}

// ---------------------------------------------------------------- QKV GEMM
// grid 768 = 8 XCD x (3 z x 4 mb x 8 nb); per XCD per z: A-panel 4x256 rows
// = 2MB + B 2MB = 4MB = L2. RoPE fused (pair (n,n^1) adjacent l4 lanes);
// q scaled log2e/8. z==2: epilogue tile transposed -> V^T [bh][d][s].
__global__ __launch_bounds__(512) void gemm_qkv_kernel(
    const _Float16* __restrict__ A, const _Float16* __restrict__ w0,
    const _Float16* __restrict__ w1, const _Float16* __restrict__ w2,
    const float* __restrict__ b0, const float* __restrict__ b1,
    const float* __restrict__ b2, _Float16* __restrict__ o0,
    _Float16* __restrict__ o1, _Float16* __restrict__ o2) {
  __shared__ _Float16 smem[73728];          // 3 x 48KB bufs / epi tile 33.8KB

  const int tid = threadIdx.x;
  const int w = tid >> 6, lane = tid & 63;
  const int l4 = lane & 15, quad = lane >> 4;
  const int wm = w >> 1, wn = w & 1;

  const int bid = blockIdx.x;
  const int xcd = bid & 7, li = bid >> 3;   // li 0..95
  const int z = li >> 5, r_ = li & 31;
  const int m0 = (xcd * 4 + (r_ & 3)) * 256;
  const int n0 = (r_ >> 2) * 128;

  const _Float16* B; const float* bias; _Float16* out;
  if (z == 0)      { B = w0; bias = b0; out = o0; }
  else if (z == 1) { B = w1; bias = b1; out = o1; }
  else             { B = w2; bias = b2; out = o2; }
  const bool dorope = z < 2;
  const float scl = (z == 0) ? 0.18033688f : 1.0f;  // log2e/8

  floatx4 acc[4][4];
  mainloop_8ph(A, B, smem, m0, n0, acc);

  // epilogue in two 128-row m-halves; waves with wm>>1==h own half h.
  _Float16* tile = smem;                    // [128][132]
  for (int h = 0; h < 2; ++h) {
    if ((wm >> 1) == h) {
#pragma unroll
      for (int nt = 0; nt < 4; ++nt) {
        const int n = n0 + wn * 64 + nt * 16 + l4;
        const float bval = bias[n];
        const int hh = n >> 6;
        float c_ = 1.f, ss = 0.f;
        if (dorope) {
          const float freq = __expf((float)(n & 31) * -0.28782314f);  // ln(1e4)/32
          float s_;
          __sincosf((float)hh * freq, &s_, &c_);
          ss = (n & 1) ? s_ : -s_;
        }
#pragma unroll
        for (int mt = 0; mt < 4; ++mt)
#pragma unroll
          for (int r = 0; r < 4; ++r) {
            float val = acc[mt][nt][r] + bval;
            const float prt = __shfl_xor(val, 1);
            if (dorope) val = (val * c_ + prt * ss) * scl;
            const int ml = (wm & 1) * 64 + mt * 16 + quad * 4 + r;
            const int nl = wn * 64 + nt * 16 + l4;
            if (z == 2) tile[nl * 132 + ml] = (_Float16)val;   // transposed
            else        tile[ml * 132 + nl] = (_Float16)val;
          }
      }
    }
    __syncthreads();
    const int mg = m0 + h * 128;
    const int bb = mg >> 12, sg = mg & 4095;
    if (z == 2) {
#pragma unroll
      for (int j = 0; j < 4; ++j) {
        const int idx = j * 512 + tid;      // 128 d-rows x 16 s-chunks
        const int row = idx >> 4, cbk = idx & 15;
        const int n = n0 + row, hh = n >> 6, dd = n & 63;
        const int s = sg + cbk * 8;
        const half8 vals = *(const half8*)(tile + row * 132 + cbk * 8);
        *(half8*)(out + (bb * 16 + hh) * 262144 + dd * 4096 + s) = vals;
      }
    } else {
#pragma unroll
      for (int j = 0; j < 4; ++j) {
        const int idx = j * 512 + tid;      // 128 s-rows x 16 d-chunks
        const int row = idx >> 4, cbk = idx & 15;
        const int n = n0 + cbk * 8, hh = n >> 6, dd = n & 63;
        const int s = sg + row;
        const half8 vals = *(const half8*)(tile + row * 132 + cbk * 8);
        *(half8*)(out + ((bb * 16 + hh) * 4096 + s) * 64 + dd) = vals;
      }
    }
    __syncthreads();
  }
}

// ---------------------------------------------------------------- out GEMM
// grid 256 = 8 XCD x (4 mb x 8 nb): exactly one block per CU.
__global__ __launch_bounds__(512) void gemm_out_kernel(
    const _Float16* __restrict__ A, const _Float16* __restrict__ B,
    const float* __restrict__ bias, float* __restrict__ out) {
  __shared__ _Float16 smem[73728];

  const int tid = threadIdx.x;
  const int w = tid >> 6, lane = tid & 63;
  const int l4 = lane & 15, quad = lane >> 4;
  const int wm = w >> 1, wn = w & 1;

  const int bid = blockIdx.x;
  const int xcd = bid & 7, li = bid >> 3;   // li 0..31
  const int m0 = (xcd * 4 + (li & 3)) * 256;
  const int n0 = (li >> 2) * 128;

  floatx4 acc[4][4];
  mainloop_8ph(A, B, smem, m0, n0, acc);

#pragma unroll
  for (int nt = 0; nt < 4; ++nt) {
    const int n = n0 + wn * 64 + nt * 16 + l4;
    const float bval = bias[n];
#pragma unroll
    for (int mt = 0; mt < 4; ++mt)
#pragma unroll
      for (int r = 0; r < 4; ++r) {
        const int m = m0 + wm * 64 + mt * 16 + quad * 4 + r;
        out[m * 1024 + n] = acc[mt][nt][r] + bval;
      }
  }
}

// ---------------------------------------------------------------- attention
// R10 verbatim (best measured / best clock-normalized). S^T formulation;
// 256 q/block; double-buffered KV staging, stage-ahead + vmcnt(8); raw
// barriers; exact per-wave band skip/mask; XCD-grouped bh; K=16 PV.
__global__ __launch_bounds__(256, 2) void attn_kernel(
    const _Float16* __restrict__ qg, const _Float16* __restrict__ kg,
    const _Float16* __restrict__ vtg, _Float16* __restrict__ ctx) {
  __shared__ _Float16 Ks[2][128 * 64];   // [buf][key][d]
  __shared__ _Float16 Vs[2][64 * 128];   // [buf][d][key] (from vt)

  const int tid = threadIdx.x;
  const int w = tid >> 6, lane = tid & 63;
  const int l4 = lane & 15, quad = lane >> 4;

  const int bid = blockIdx.x;
  const int xcd = bid & 7, li = bid >> 3;   // li 0..63
  const int bh = xcd * 4 + (li >> 4);       // XCD owns 4 heads -> KV L2-fit
  const int q0 = (li & 15) * 256;

  const _Float16* qbh = qg + bh * 262144;
  const _Float16* kbh = kg + bh * 262144;
  const _Float16* vbh = vtg + bh * 262144;

  // Q as B-operand frags: query = q0 + sub*128 + w*32 + nt*16 + l4
  half8 qf[2][2][2];
#pragma unroll
  for (int sub = 0; sub < 2; ++sub)
#pragma unroll
    for (int nt = 0; nt < 2; ++nt)
#pragma unroll
      for (int ks = 0; ks < 2; ++ks)
        qf[sub][nt][ks] = *(const half8*)(qbh + (q0 + sub * 128 + w * 32 + nt * 16 + l4) * 64 +
                                          ks * 32 + quad * 8);

  const floatx4 zero = {0.f, 0.f, 0.f, 0.f};
  floatx4 OT[2][4][2];               // [sub][d-tile][q-tile]
  float l_st[2][2];                  // lane-local partial (this quad's keys)
#pragma unroll
  for (int sub = 0; sub < 2; ++sub) {
#pragma unroll
    for (int md = 0; md < 4; ++md)
#pragma unroll
      for (int nt = 0; nt < 2; ++nt) OT[sub][md][nt] = zero;
#pragma unroll
    for (int nt = 0; nt < 2; ++nt) l_st[sub][nt] = 0.f;
  }

  // valid kv-tile range: kv0(t) = q0 - 256 + t*128 in [0, 3968]
  const int tb = (q0 == 0) ? 2 : 0;
  const int te = (q0 == 3840) ? 3 : 5;

  // stage one 128-key tile (K + V^T slab) into buffer b_: 8 loads/thread.
  auto stage = [&](int b_, int kv0_) {
#pragma unroll
    for (int i = 0; i < 4; ++i) {
      const int p = i * 256 + tid;
      const int rk = p >> 3, ck = (p & 7) ^ (rk & 7);
      async_copy16(kbh + (kv0_ + rk) * 64 + ck * 8, &Ks[b_][(i * 256 + w * 64) * 8]);
      const int rv = p >> 4, cv = (p & 15) ^ (rv & 7);
      async_copy16(vbh + rv * 4096 + kv0_ + cv * 8, &Vs[b_][(i * 256 + w * 64) * 8]);
    }
  };

  stage(tb & 1, q0 - 256 + tb * 128);

  for (int t = tb; t <= te; ++t) {
    const int kv0 = q0 - 256 + t * 128;
    if (t < te) {
      stage((t + 1) & 1, kv0 + 128);
      asm volatile("s_waitcnt vmcnt(8)" ::: "memory");  // tile t landed; t+1 in flight
    } else {
      asm volatile("s_waitcnt vmcnt(0)" ::: "memory");  // last tile: drain
    }
    __builtin_amdgcn_s_barrier();
    const _Float16* Kc = Ks[t & 1];
    const _Float16* Vc = Vs[t & 1];

#pragma unroll
    for (int sub = 0; sub < 2; ++sub) {
      const int qbase = q0 + sub * 128 + w * 32;   // this wave's 32 queries
#pragma unroll
      for (int hf = 0; hf < 2; ++hf) {
        const int kb = hf * 64;
        const int k_lo = kv0 + kb, k_hi = k_lo + 63;
        // wave-uniform: all 64 keys outside band for all 32 queries -> skip
        if (k_lo - (qbase + 31) > 256 || k_hi - qbase < -256) continue;
        const bool needm = (k_lo - (qbase + 31) < -256) || (k_hi - qbase > 256);

        floatx4 ST[4][2];
#pragma unroll
        for (int m = 0; m < 4; ++m)
#pragma unroll
          for (int nt = 0; nt < 2; ++nt) ST[m][nt] = zero;
#pragma unroll
        for (int ks = 0; ks < 2; ++ks)
#pragma unroll
          for (int m = 0; m < 4; ++m) {
            const half8 kf = *(const half8*)(Kc + (kb + m * 16 + l4) * 64 +
                                             ((ks * 4 + quad) ^ (l4 & 7)) * 8);
#pragma unroll
            for (int nt = 0; nt < 2; ++nt)
              ST[m][nt] = __builtin_amdgcn_mfma_f32_16x16x32_f16(kf, qf[sub][nt][ks], ST[m][nt], 0, 0, 0);
          }

        if (needm) {  // band mask |key - query| <= 256
#pragma unroll
          for (int m = 0; m < 4; ++m)
#pragma unroll
            for (int r = 0; r < 4; ++r) {
              const int key = kv0 + kb + m * 16 + quad * 4 + r;
#pragma unroll
              for (int nt = 0; nt < 2; ++nt) {
                const int d = key - (qbase + nt * 16 + l4);
                if (d < -256 || d > 256) ST[m][nt][r] = -1e30f;
              }
            }
        }

        // P = exp2(S - 4); lane-local l accumulation (no max, no rescale)
#pragma unroll
        for (int nt = 0; nt < 2; ++nt) {
          float rs = 0.f;
#pragma unroll
          for (int m = 0; m < 4; ++m)
#pragma unroll
            for (int r = 0; r < 4; ++r) {
              const float pv = exp2f(ST[m][nt][r] - 4.0f);
              ST[m][nt][r] = pv;
              rs += pv;
            }
          l_st[sub][nt] += rs;
        }

        // O^T += V^T P^T; P B-frag = packed ST C-frag (k=quad*4+j)
#pragma unroll
        for (int m = 0; m < 4; ++m) {
          half4v pb[2];
#pragma unroll
          for (int nt = 0; nt < 2; ++nt) {
            const auto lo = __builtin_amdgcn_cvt_pkrtz(ST[m][nt][0], ST[m][nt][1]);
            const auto hi = __builtin_amdgcn_cvt_pkrtz(ST[m][nt][2], ST[m][nt][3]);
            pb[nt][0] = (_Float16)lo[0]; pb[nt][1] = (_Float16)lo[1];
            pb[nt][2] = (_Float16)hi[0]; pb[nt][3] = (_Float16)hi[1];
          }
#pragma unroll
          for (int md = 0; md < 4; ++md) {
            const half4v vf = *(const half4v*)(Vc + (md * 16 + l4) * 128 +
                                               (((hf * 8 + m * 2 + (quad >> 1)) ^ (l4 & 7)) * 8 +
                                                (quad & 1) * 4));
#pragma unroll
            for (int nt = 0; nt < 2; ++nt)
              OT[sub][md][nt] = __builtin_amdgcn_mfma_f32_16x16x16f16(vf, pb[nt], OT[sub][md][nt], 0, 0, 0);
          }
        }
      }
    }

    if (t < te) {
      // trailing barrier: my ds_reads of this buffer must retire before any
      // wave stages into it next iteration. NOT __syncthreads (vmcnt drain).
      asm volatile("s_waitcnt lgkmcnt(0)" ::: "memory");
      __builtin_amdgcn_sched_barrier(0);
      __builtin_amdgcn_s_barrier();
    }
  }

  // epilogue: reduce l across quads (keys were quad-distributed), then scale.
  const int b = bh >> 4, hh = bh & 15;
#pragma unroll
  for (int sub = 0; sub < 2; ++sub)
#pragma unroll
    for (int nt = 0; nt < 2; ++nt) {
      float lt = l_st[sub][nt];
      lt += __shfl_xor(lt, 16);
      lt += __shfl_xor(lt, 32);
      const float inv_l = 1.f / lt;
      const int s = q0 + sub * 128 + w * 32 + nt * 16 + l4;
#pragma unroll
      for (int md = 0; md < 4; ++md) {
        half4v o;
#pragma unroll
        for (int r = 0; r < 4; ++r) o[r] = (_Float16)(OT[sub][md][nt][r] * inv_l);
        *(half4v*)(ctx + (b * 4096 + s) * 1024 + hh * 64 + md * 16 + quad * 4) = o;
      }
    }
}

// ---------------------------------------------------------------- launch
extern "C" void kernel_launch(void* const* d_in, const int* in_sizes, int n_in,
                              void* d_out, int out_size, void* d_ws, size_t ws_size,
                              hipStream_t stream) {
  const float* x  = (const float*)d_in[0];
  const float* Wq = (const float*)d_in[1];
  const float* bq = (const float*)d_in[2];
  const float* Wk = (const float*)d_in[3];
  const float* bk = (const float*)d_in[4];
  const float* Wv = (const float*)d_in[5];
  const float* bv = (const float*)d_in[6];
  const float* Wo = (const float*)d_in[7];
  const float* bo = (const float*)d_in[8];

  _Float16* ws   = (_Float16*)d_ws;       // all offsets in halfs
  _Float16* xh   = ws;                    // 8388608
  _Float16* wqh  = ws + 8388608;          // 1048576 each
  _Float16* wkh  = ws + 9437184;
  _Float16* wvh  = ws + 10485760;
  _Float16* woh  = ws + 11534336;
  _Float16* qh   = ws + 12582912;         // [b,h,s,d] fp16, rope+scale applied
  _Float16* kh   = ws + 20971520;         // [b,h,s,d] fp16, rope applied
  _Float16* vth  = ws + 29360128;         // [b,h,d,s] fp16 (written directly)
  _Float16* ctxh = xh;                    // reuse: x dead after QKV GEMM

  convert_kernel<<<12288, 256, 0, stream>>>(x, Wq, Wk, Wv, Wo, ws);
  gemm_qkv_kernel<<<768, 512, 0, stream>>>(xh, wqh, wkh, wvh,
                                           bq, bk, bv, qh, kh, vth);
  attn_kernel<<<512, 256, 0, stream>>>(qh, kh, vth, ctxh);
  gemm_out_kernel<<<256, 512, 0, stream>>>(ctxh, woh, bo, (float*)d_out);
}

// Round 11
// 229.765 us; speedup vs baseline: 1.0966x; 1.0966x over previous
//
#include <hip/hip_runtime.h>

// LongformerAttention on MI355X (gfx950), fp16 MFMA pipeline, round 18.
// R18 = R10 RESTORED VERBATIM (best measured: 226.0us; best clock-normalized
// 3.398 x qkv-anchor). Session ledger: ten experiments, one win (R10's attn
// stage-ahead double-buffer + counted vmcnt, -27us), nine reversions:
//   R8/R12/R17 GEMM pipelining (1-2 blocks/CU loses to 4-block implicit
//   overlap), R11 BK=32 swizzle (25x bank conflicts), R13/R16 out-tile
//   128x64 (1.5x staged bytes/FLOP), R13 attn setprio (lockstep regime =>
//   negative, m190), R14 PV K=32 (neutral-negative), R15 softmax-MFMA
//   tricks (serial MFMA on pack->PV critical path, +7us).
// Structure: R7 GEMMs (single-buffer BK=64, 128x128 tile, chunk-swizzled
// LDS, MfmaUtil 33% anchor, 4 blocks/CU); attn 256q/block with dbuf KV
// staging, stage-ahead + vmcnt(8), raw barriers (no vmcnt(0) drain), exact
// per-wave band skip/mask, XCD-grouped bh (KV L2-fit); RoPE fused in qkv
// epilogue; V^T written directly by qkv's z==2 transposed epilogue.

typedef _Float16 half8 __attribute__((ext_vector_type(8)));
typedef _Float16 half4v __attribute__((ext_vector_type(4)));
typedef float floatx4 __attribute__((ext_vector_type(4)));

typedef __attribute__((address_space(3))) unsigned int lds_u32;
typedef const __attribute__((address_space(1))) unsigned int glb_u32;

__device__ __forceinline__ void async_copy16(const void* g, void* l) {
  // global -> LDS direct, 16 B/lane. LDS dest = wave-uniform base + lane*16.
  __builtin_amdgcn_global_load_lds((glb_u32*)g, (lds_u32*)l, 16, 0, 0);
}

// ---------------------------------------------------------------- convert
__global__ __launch_bounds__(256) void convert_kernel(
    const float* __restrict__ x, const float* __restrict__ wq,
    const float* __restrict__ wk, const float* __restrict__ wv,
    const float* __restrict__ wo, _Float16* __restrict__ dst) {
  const int e0 = (blockIdx.x * 256 + threadIdx.x) * 4;
  const float* src; int off;
  if      (e0 <  8388608) { src = x;  off = e0; }
  else if (e0 <  9437184) { src = wq; off = e0 -  8388608; }
  else if (e0 < 10485760) { src = wk; off = e0 -  9437184; }
  else if (e0 < 11534336) { src = wv; off = e0 - 10485760; }
  else                    { src = wo; off = e0 - 11534336; }
  const float4 f = *(const float4*)(src + off);
  half4v h;
  h[0] = (_Float16)f.x; h[1] = (_Float16)f.y;
  h[2] = (_Float16)f.z; h[3] = (_Float16)f.w;
  *(half4v*)(dst + e0) = h;
}

// ---------------------------------------------------------------- QKV GEMM
// R7 structure (proven: MfmaUtil 33%, conflicts = epilogue-only).
// out[m,n] = sum_k A[m,k]*W[n,k] + bias[n]; RoPE fused in epilogue for q,k
// (pair (n,n^1) in adjacent l4 lanes -> __shfl_xor(val,1)); q scaled log2e/8.
// z==2 (V): epilogue LDS tile stored transposed, output written as V^T
// [bh][d][s] directly.
__global__ __launch_bounds__(256, 2) void gemm_qkv_kernel(
    const _Float16* __restrict__ A, const _Float16* __restrict__ w0,
    const _Float16* __restrict__ w1, const _Float16* __restrict__ w2,
    const float* __restrict__ b0, const float* __restrict__ b1,
    const float* __restrict__ b2, _Float16* __restrict__ o0,
    _Float16* __restrict__ o1, _Float16* __restrict__ o2) {
  __shared__ _Float16 smem[17408];          // staging 32 KB / epi tile 33.8 KB
  _Float16* As = smem;                      // [128][64] chunk-swizzled
  _Float16* Bs = smem + 8192;

  const int tid = threadIdx.x;
  const int w = tid >> 6, lane = tid & 63;
  const int l4 = lane & 15, quad = lane >> 4;
  const int wm = w & 1, wn = w >> 1;

  const int bid = blockIdx.x;
  const int xcd = bid & 7, li = bid >> 3;   // li in 0..191
  const int z = li >> 6, r_ = li & 63;
  const int n_l = r_ >> 3, m_l = r_ & 7;
  const int m0 = (xcd * 8 + m_l) * 128;
  const int n0 = n_l * 128;

  const _Float16* B; const float* bias; _Float16* out;
  if (z == 0)      { B = w0; bias = b0; out = o0; }
  else if (z == 1) { B = w1; bias = b1; out = o1; }
  else             { B = w2; bias = b2; out = o2; }
  const bool dorope = z < 2;
  const float scl = (z == 0) ? 0.18033688f : 1.0f;  // log2e/8

  const floatx4 zero = {0.f, 0.f, 0.f, 0.f};
  floatx4 acc[4][4];
#pragma unroll
  for (int i = 0; i < 4; ++i)
#pragma unroll
    for (int j = 0; j < 4; ++j) acc[i][j] = zero;

  for (int kt = 0; kt < 16; ++kt) {
    const int k0 = kt * 64;
#pragma unroll
    for (int i = 0; i < 4; ++i) {
      const int p = i * 256 + tid;          // 128 rows x 8 chunks
      const int r = p >> 3;
      const int c = (p & 7) ^ (r & 7);      // 3-bit XOR chunk swizzle
      async_copy16(A + (m0 + r) * 1024 + k0 + c * 8, As + (i * 256 + w * 64) * 8);
      async_copy16(B + (n0 + r) * 1024 + k0 + c * 8, Bs + (i * 256 + w * 64) * 8);
    }
    __syncthreads();
#pragma unroll
    for (int ks = 0; ks < 2; ++ks) {
      half8 af[4], bf[4];
#pragma unroll
      for (int mt = 0; mt < 4; ++mt)
        af[mt] = *(const half8*)(As + (wm * 64 + mt * 16 + l4) * 64 +
                                 (((ks * 4 + quad) ^ (l4 & 7)) * 8));
#pragma unroll
      for (int nt = 0; nt < 4; ++nt)
        bf[nt] = *(const half8*)(Bs + (wn * 64 + nt * 16 + l4) * 64 +
                                 (((ks * 4 + quad) ^ (l4 & 7)) * 8));
#pragma unroll
      for (int mt = 0; mt < 4; ++mt)
#pragma unroll
        for (int nt = 0; nt < 4; ++nt)
          acc[mt][nt] = __builtin_amdgcn_mfma_f32_16x16x32_f16(af[mt], bf[nt], acc[mt][nt], 0, 0, 0);
    }
    __syncthreads();
  }

  // epilogue: bias (+RoPE) in C-layout -> LDS tile -> coalesced half8 stores.
  // q,k: tile[m][n], store [bh][s][d]. V: tile[n][m], store V^T [bh][d][s].
  _Float16* tile = smem;                    // [128][132]
#pragma unroll
  for (int nt = 0; nt < 4; ++nt) {
    const int n = n0 + wn * 64 + nt * 16 + l4;
    const float bval = bias[n];
    const int hh = n >> 6;
    float c_ = 1.f, ss = 0.f;
    if (dorope) {
      const float freq = __expf((float)(n & 31) * -0.28782314f);  // ln(1e4)/32
      float s_;
      __sincosf((float)hh * freq, &s_, &c_);
      ss = (n & 1) ? s_ : -s_;
    }
#pragma unroll
    for (int mt = 0; mt < 4; ++mt)
#pragma unroll
      for (int r = 0; r < 4; ++r) {
        float val = acc[mt][nt][r] + bval;
        const float prt = __shfl_xor(val, 1);
        if (dorope) val = (val * c_ + prt * ss) * scl;
        const int ml = wm * 64 + mt * 16 + quad * 4 + r;
        const int nl = wn * 64 + nt * 16 + l4;
        if (z == 2) tile[nl * 132 + ml] = (_Float16)val;   // transposed
        else        tile[ml * 132 + nl] = (_Float16)val;
      }
  }
  __syncthreads();
  if (z == 2) {
#pragma unroll
    for (int j = 0; j < 8; ++j) {
      const int idx = j * 256 + tid;        // 128 d-rows x 16 s-chunks
      const int row = idx >> 4, cb = idx & 15;
      const int n = n0 + row, hh = n >> 6, dd = n & 63;
      const int m = m0 + cb * 8, bb = m >> 12, s = m & 4095;
      const half8 vals = *(const half8*)(tile + row * 132 + cb * 8);
      *(half8*)(out + (bb * 16 + hh) * 262144 + dd * 4096 + s) = vals;
    }
  } else {
#pragma unroll
    for (int j = 0; j < 8; ++j) {
      const int idx = j * 256 + tid;        // 128 s-rows x 16 d-chunks
      const int row = idx >> 4, cb = idx & 15;
      const int n = n0 + cb * 8, hh = n >> 6, dd = n & 63;
      const int m = m0 + row, bb = m >> 12, s = m & 4095;
      const half8 vals = *(const half8*)(tile + row * 132 + cb * 8);
      *(half8*)(out + ((bb * 16 + hh) * 4096 + s) * 64 + dd) = vals;
    }
  }
}

// ---------------------------------------------------------------- out GEMM
// R7 structure verbatim (128x128 tiles, grid 512).
__global__ __launch_bounds__(256, 2) void gemm_out_kernel(
    const _Float16* __restrict__ A, const _Float16* __restrict__ B,
    const float* __restrict__ bias, float* __restrict__ out) {
  __shared__ _Float16 smem[16384];
  _Float16* As = smem;
  _Float16* Bs = smem + 8192;

  const int tid = threadIdx.x;
  const int w = tid >> 6, lane = tid & 63;
  const int l4 = lane & 15, quad = lane >> 4;
  const int wm = w & 1, wn = w >> 1;

  const int bid = blockIdx.x;
  const int xcd = bid & 7, li = bid >> 3;   // li in 0..63
  const int n_l = li >> 3, m_l = li & 7;
  const int m0 = (xcd * 8 + m_l) * 128;
  const int n0 = n_l * 128;

  const floatx4 zero = {0.f, 0.f, 0.f, 0.f};
  floatx4 acc[4][4];
#pragma unroll
  for (int i = 0; i < 4; ++i)
#pragma unroll
    for (int j = 0; j < 4; ++j) acc[i][j] = zero;

  for (int kt = 0; kt < 16; ++kt) {
    const int k0 = kt * 64;
#pragma unroll
    for (int i = 0; i < 4; ++i) {
      const int p = i * 256 + tid;
      const int r = p >> 3;
      const int c = (p & 7) ^ (r & 7);
      async_copy16(A + (m0 + r) * 1024 + k0 + c * 8, As + (i * 256 + w * 64) * 8);
      async_copy16(B + (n0 + r) * 1024 + k0 + c * 8, Bs + (i * 256 + w * 64) * 8);
    }
    __syncthreads();
#pragma unroll
    for (int ks = 0; ks < 2; ++ks) {
      half8 af[4], bf[4];
#pragma unroll
      for (int mt = 0; mt < 4; ++mt)
        af[mt] = *(const half8*)(As + (wm * 64 + mt * 16 + l4) * 64 +
                                 (((ks * 4 + quad) ^ (l4 & 7)) * 8));
#pragma unroll
      for (int nt = 0; nt < 4; ++nt)
        bf[nt] = *(const half8*)(Bs + (wn * 64 + nt * 16 + l4) * 64 +
                                 (((ks * 4 + quad) ^ (l4 & 7)) * 8));
#pragma unroll
      for (int mt = 0; mt < 4; ++mt)
#pragma unroll
        for (int nt = 0; nt < 4; ++nt)
          acc[mt][nt] = __builtin_amdgcn_mfma_f32_16x16x32_f16(af[mt], bf[nt], acc[mt][nt], 0, 0, 0);
    }
    __syncthreads();
  }

#pragma unroll
  for (int nt = 0; nt < 4; ++nt) {
    const int n = n0 + wn * 64 + nt * 16 + l4;
    const float bval = bias[n];
#pragma unroll
    for (int mt = 0; mt < 4; ++mt)
#pragma unroll
      for (int r = 0; r < 4; ++r) {
        const int m = m0 + wm * 64 + mt * 16 + quad * 4 + r;
        out[m * 1024 + n] = acc[mt][nt][r] + bval;
      }
  }
}

// ---------------------------------------------------------------- attention
// R10 verbatim (the session's one verified win, -27us). S^T formulation:
// ST = K*Q^T per 64-key half-tile; ST C-layout IS the B-operand layout of
// mfma_f32_16x16x16f16 -> P feeds PV from registers. 256 q/block; double-
// buffered KV staging with stage-ahead + counted vmcnt(8); raw s_barrier
// (no vmcnt(0) drain); exact per-wave band skip/mask; XCD-grouped bh
// (4 heads/XCD -> 4MB KV = L2-fit). Softmax: STATIC shift P = exp2(S-4),
// lane-local l, quad-reduce at epilogue.
__global__ __launch_bounds__(256, 2) void attn_kernel(
    const _Float16* __restrict__ qg, const _Float16* __restrict__ kg,
    const _Float16* __restrict__ vtg, _Float16* __restrict__ ctx) {
  __shared__ _Float16 Ks[2][128 * 64];   // [buf][key][d]
  __shared__ _Float16 Vs[2][64 * 128];   // [buf][d][key] (from vt)

  const int tid = threadIdx.x;
  const int w = tid >> 6, lane = tid & 63;
  const int l4 = lane & 15, quad = lane >> 4;

  const int bid = blockIdx.x;
  const int xcd = bid & 7, li = bid >> 3;   // li 0..63
  const int bh = xcd * 4 + (li >> 4);       // XCD owns 4 heads -> KV L2-fit
  const int q0 = (li & 15) * 256;

  const _Float16* qbh = qg + bh * 262144;
  const _Float16* kbh = kg + bh * 262144;
  const _Float16* vbh = vtg + bh * 262144;

  // Q as B-operand frags: query = q0 + sub*128 + w*32 + nt*16 + l4
  half8 qf[2][2][2];
#pragma unroll
  for (int sub = 0; sub < 2; ++sub)
#pragma unroll
    for (int nt = 0; nt < 2; ++nt)
#pragma unroll
      for (int ks = 0; ks < 2; ++ks)
        qf[sub][nt][ks] = *(const half8*)(qbh + (q0 + sub * 128 + w * 32 + nt * 16 + l4) * 64 +
                                          ks * 32 + quad * 8);

  const floatx4 zero = {0.f, 0.f, 0.f, 0.f};
  floatx4 OT[2][4][2];               // [sub][d-tile][q-tile]
  float l_st[2][2];                  // lane-local partial (this quad's keys)
#pragma unroll
  for (int sub = 0; sub < 2; ++sub) {
#pragma unroll
    for (int md = 0; md < 4; ++md)
#pragma unroll
      for (int nt = 0; nt < 2; ++nt) OT[sub][md][nt] = zero;
#pragma unroll
    for (int nt = 0; nt < 2; ++nt) l_st[sub][nt] = 0.f;
  }

  // valid kv-tile range: kv0(t) = q0 - 256 + t*128 in [0, 3968]
  const int tb = (q0 == 0) ? 2 : 0;
  const int te = (q0 == 3840) ? 3 : 5;

  // stage one 128-key tile (K + V^T slab) into buffer b_: 8 loads/thread.
  auto stage = [&](int b_, int kv0_) {
#pragma unroll
    for (int i = 0; i < 4; ++i) {
      const int p = i * 256 + tid;
      const int rk = p >> 3, ck = (p & 7) ^ (rk & 7);
      async_copy16(kbh + (kv0_ + rk) * 64 + ck * 8, &Ks[b_][(i * 256 + w * 64) * 8]);
      const int rv = p >> 4, cv = (p & 15) ^ (rv & 7);
      async_copy16(vbh + rv * 4096 + kv0_ + cv * 8, &Vs[b_][(i * 256 + w * 64) * 8]);
    }
  };

  stage(tb & 1, q0 - 256 + tb * 128);

  for (int t = tb; t <= te; ++t) {
    const int kv0 = q0 - 256 + t * 128;
    if (t < te) {
      stage((t + 1) & 1, kv0 + 128);
      asm volatile("s_waitcnt vmcnt(8)" ::: "memory");  // tile t landed; t+1 in flight
    } else {
      asm volatile("s_waitcnt vmcnt(0)" ::: "memory");  // last tile: drain
    }
    __builtin_amdgcn_s_barrier();
    const _Float16* Kc = Ks[t & 1];
    const _Float16* Vc = Vs[t & 1];

#pragma unroll
    for (int sub = 0; sub < 2; ++sub) {
      const int qbase = q0 + sub * 128 + w * 32;   // this wave's 32 queries
#pragma unroll
      for (int hf = 0; hf < 2; ++hf) {
        const int kb = hf * 64;
        const int k_lo = kv0 + kb, k_hi = k_lo + 63;
        // wave-uniform: all 64 keys outside band for all 32 queries -> skip
        if (k_lo - (qbase + 31) > 256 || k_hi - qbase < -256) continue;
        const bool needm = (k_lo - (qbase + 31) < -256) || (k_hi - qbase > 256);

        floatx4 ST[4][2];
#pragma unroll
        for (int m = 0; m < 4; ++m)
#pragma unroll
          for (int nt = 0; nt < 2; ++nt) ST[m][nt] = zero;
#pragma unroll
        for (int ks = 0; ks < 2; ++ks)
#pragma unroll
          for (int m = 0; m < 4; ++m) {
            const half8 kf = *(const half8*)(Kc + (kb + m * 16 + l4) * 64 +
                                             ((ks * 4 + quad) ^ (l4 & 7)) * 8);
#pragma unroll
            for (int nt = 0; nt < 2; ++nt)
              ST[m][nt] = __builtin_amdgcn_mfma_f32_16x16x32_f16(kf, qf[sub][nt][ks], ST[m][nt], 0, 0, 0);
          }

        if (needm) {  // band mask |key - query| <= 256
#pragma unroll
          for (int m = 0; m < 4; ++m)
#pragma unroll
            for (int r = 0; r < 4; ++r) {
              const int key = kv0 + kb + m * 16 + quad * 4 + r;
#pragma unroll
              for (int nt = 0; nt < 2; ++nt) {
                const int d = key - (qbase + nt * 16 + l4);
                if (d < -256 || d > 256) ST[m][nt][r] = -1e30f;
              }
            }
        }

        // P = exp2(S - 4); lane-local l accumulation (no max, no rescale)
#pragma unroll
        for (int nt = 0; nt < 2; ++nt) {
          float rs = 0.f;
#pragma unroll
          for (int m = 0; m < 4; ++m)
#pragma unroll
            for (int r = 0; r < 4; ++r) {
              const float pv = exp2f(ST[m][nt][r] - 4.0f);
              ST[m][nt][r] = pv;
              rs += pv;
            }
          l_st[sub][nt] += rs;
        }

        // O^T += V^T P^T; P B-frag = packed ST C-frag (k=quad*4+j)
#pragma unroll
        for (int m = 0; m < 4; ++m) {
          half4v pb[2];
#pragma unroll
          for (int nt = 0; nt < 2; ++nt) {
            const auto lo = __builtin_amdgcn_cvt_pkrtz(ST[m][nt][0], ST[m][nt][1]);
            const auto hi = __builtin_amdgcn_cvt_pkrtz(ST[m][nt][2], ST[m][nt][3]);
            pb[nt][0] = (_Float16)lo[0]; pb[nt][1] = (_Float16)lo[1];
            pb[nt][2] = (_Float16)hi[0]; pb[nt][3] = (_Float16)hi[1];
          }
#pragma unroll
          for (int md = 0; md < 4; ++md) {
            const half4v vf = *(const half4v*)(Vc + (md * 16 + l4) * 128 +
                                               (((hf * 8 + m * 2 + (quad >> 1)) ^ (l4 & 7)) * 8 +
                                                (quad & 1) * 4));
#pragma unroll
            for (int nt = 0; nt < 2; ++nt)
              OT[sub][md][nt] = __builtin_amdgcn_mfma_f32_16x16x16f16(vf, pb[nt], OT[sub][md][nt], 0, 0, 0);
          }
        }
      }
    }

    if (t < te) {
      // trailing barrier: my ds_reads of this buffer must retire before any
      // wave stages into it next iteration. NOT __syncthreads (vmcnt drain).
      asm volatile("s_waitcnt lgkmcnt(0)" ::: "memory");
      __builtin_amdgcn_sched_barrier(0);
      __builtin_amdgcn_s_barrier();
    }
  }

  // epilogue: reduce l across quads (keys were quad-distributed), then scale.
  const int b = bh >> 4, hh = bh & 15;
#pragma unroll
  for (int sub = 0; sub < 2; ++sub)
#pragma unroll
    for (int nt = 0; nt < 2; ++nt) {
      float lt = l_st[sub][nt];
      lt += __shfl_xor(lt, 16);
      lt += __shfl_xor(lt, 32);
      const float inv_l = 1.f / lt;
      const int s = q0 + sub * 128 + w * 32 + nt * 16 + l4;
#pragma unroll
      for (int md = 0; md < 4; ++md) {
        half4v o;
#pragma unroll
        for (int r = 0; r < 4; ++r) o[r] = (_Float16)(OT[sub][md][nt][r] * inv_l);
        *(half4v*)(ctx + (b * 4096 + s) * 1024 + hh * 64 + md * 16 + quad * 4) = o;
      }
    }
}

// ---------------------------------------------------------------- launch
extern "C" void kernel_launch(void* const* d_in, const int* in_sizes, int n_in,
                              void* d_out, int out_size, void* d_ws, size_t ws_size,
                              hipStream_t stream) {
  const float* x  = (const float*)d_in[0];
  const float* Wq = (const float*)d_in[1];
  const float* bq = (const float*)d_in[2];
  const float* Wk = (const float*)d_in[3];
  const float* bk = (const float*)d_in[4];
  const float* Wv = (const float*)d_in[5];
  const float* bv = (const float*)d_in[6];
  const float* Wo = (const float*)d_in[7];
  const float* bo = (const float*)d_in[8];

  _Float16* ws   = (_Float16*)d_ws;       // all offsets in halfs
  _Float16* xh   = ws;                    // 8388608
  _Float16* wqh  = ws + 8388608;          // 1048576 each
  _Float16* wkh  = ws + 9437184;
  _Float16* wvh  = ws + 10485760;
  _Float16* woh  = ws + 11534336;
  _Float16* qh   = ws + 12582912;         // [b,h,s,d] fp16, rope+scale applied
  _Float16* kh   = ws + 20971520;         // [b,h,s,d] fp16, rope applied
  _Float16* vth  = ws + 29360128;         // [b,h,d,s] fp16 (written directly)
  _Float16* ctxh = xh;                    // reuse: x dead after QKV GEMM

  convert_kernel<<<12288, 256, 0, stream>>>(x, Wq, Wk, Wv, Wo, ws);
  gemm_qkv_kernel<<<1536, 256, 0, stream>>>(xh, wqh, wkh, wvh,
                                            bq, bk, bv, qh, kh, vth);
  attn_kernel<<<512, 256, 0, stream>>>(qh, kh, vth, ctxh);
  gemm_out_kernel<<<512, 256, 0, stream>>>(ctxh, woh, bo, (float*)d_out);
}